// Round 4
// baseline (103.602 us; speedup 1.0000x reference)
//
#include <hip/hip_runtime.h>

#define N 2048
#define ZD 64

typedef float f32x4 __attribute__((ext_vector_type(4)));
typedef float f32x2 __attribute__((ext_vector_type(2)));

// Fully fused: each block recomputes its own P/Q tiles from z,W1 (no pT
// workspace, no separate projection kernel, one graph node fewer).
//   P[i][c] = b1[c] + sum_d z[i][d] W1[d][c]          (bit-identical to old proj)
//   Q[j][c] =         sum_d z[j][d] W1[64+d][c]
//   out[i][j] = sigmoid(0.5*(ri + rj + sum_c |P+Q|*w2[c]) + b2)
// W1 columns are wave-uniform -> scalar-pipe s_load_dwordx16 traffic only.
__global__ __launch_bounds__(256) void edge_fused(
    const float* __restrict__ z, const float* __restrict__ W1,
    const float* __restrict__ b1, const float* __restrict__ W2,
    const float* __restrict__ b2, float* __restrict__ out)
{
    __shared__ float ash[64][64];    // P^T tile: ash[c][i_local]
    __shared__ float bsh[64][128];   // Q^T tile: bsh[c][j_local]
    __shared__ float w2s[64];
    __shared__ float ris[64];
    __shared__ float rjs[128];
    __shared__ float rip[4][64];     // rank-1 partials (4 col-groups)
    __shared__ float rjp[2][128];

    const int t = threadIdx.x;
    const int i0 = blockIdx.y * 64;
    const int j0 = blockIdx.x * 128;

    // ---- Phase 1a: P tile. lane i = t&63, wave colg = t>>6 owns 16 cols ----
    {
        const int li = t & 63;
        const int colbase = __builtin_amdgcn_readfirstlane(t >> 6) << 4;
        const f32x4* zrow = (const f32x4*)(z + (i0 + li) * ZD);
        float a[16];
        #pragma unroll
        for (int cc = 0; cc < 16; ++cc) a[cc] = b1[colbase + cc];
        #pragma unroll 4
        for (int dq = 0; dq < 16; ++dq) {
            f32x4 zv = zrow[dq];                       // L1/L2-hot, per-lane
            #pragma unroll
            for (int dd = 0; dd < 4; ++dd) {
                const int d = dq * 4 + dd;
                const float zd = zv[dd];
                const float* w1r = W1 + d * 64 + colbase;   // uniform -> s_load x16
                #pragma unroll
                for (int cc = 0; cc < 16; ++cc)
                    a[cc] = fmaf(zd, w1r[cc], a[cc]);
            }
        }
        float part = 0.0f;
        #pragma unroll
        for (int cc = 0; cc < 16; ++cc) {
            ash[colbase + cc][li] = a[cc];             // banks = li&31: 2-way, free
            part = fmaf(a[cc], W2[colbase + cc], part);
        }
        rip[colbase >> 4][li] = part;
    }

    // ---- Phase 1b: Q tile. lane j = t&127, group t>>7 owns 32 cols ----
    {
        const int lj = t & 127;
        const int qbase = __builtin_amdgcn_readfirstlane(t >> 7) << 5;
        const f32x4* zrow = (const f32x4*)(z + (j0 + lj) * ZD);
        float a[32];
        #pragma unroll
        for (int cc = 0; cc < 32; ++cc) a[cc] = 0.0f;
        #pragma unroll 4
        for (int dq = 0; dq < 16; ++dq) {
            f32x4 zv = zrow[dq];
            #pragma unroll
            for (int dd = 0; dd < 4; ++dd) {
                const int d = dq * 4 + dd;
                const float zd = zv[dd];
                const float* w1r = W1 + (64 + d) * 64 + qbase;  // uniform
                #pragma unroll
                for (int cc = 0; cc < 32; ++cc)
                    a[cc] = fmaf(zd, w1r[cc], a[cc]);
            }
        }
        float part = 0.0f;
        #pragma unroll
        for (int cc = 0; cc < 32; ++cc) {
            bsh[qbase + cc][lj] = a[cc];               // banks = lj&31: 2-way, free
            part = fmaf(a[cc], W2[qbase + cc], part);
        }
        rjp[qbase >> 5][lj] = part;
    }
    if (t >= 192) w2s[t - 192] = W2[t - 192];
    __syncthreads();

    if (t < 64)       ris[t] = ((rip[0][t] + rip[1][t]) + rip[2][t]) + rip[3][t];
    else if (t < 192) rjs[t - 64] = rjp[0][t - 64] + rjp[1][t - 64];
    __syncthreads();

    // ---- Phase 2: identical abs-trick k-loop as the proven R1/R3 kernel ----
    const int tx = t & 15, ty = t >> 4;
    float acc[4][8];
    #pragma unroll
    for (int r = 0; r < 4; ++r)
        #pragma unroll
        for (int c = 0; c < 8; ++c) acc[r][c] = 0.0f;

    #pragma unroll 4
    for (int k4 = 0; k4 < 64; k4 += 4) {
        f32x4 wv = *(const f32x4*)&w2s[k4];
        #pragma unroll
        for (int kk = 0; kk < 4; ++kk) {
            const int k = k4 + kk;
            f32x4 av  = *(const f32x4*)&ash[k][ty * 4];        // 4 rows, bcast over tx
            f32x4 bv0 = *(const f32x4*)&bsh[k][tx * 4];        // 16 lanes x 16B
            f32x4 bv1 = *(const f32x4*)&bsh[k][64 + tx * 4];
            const float w = wv[kk];
            #pragma unroll
            for (int r = 0; r < 4; ++r) {
                f32x2 ar = { av[r], av[r] };                   // splat for pk_add
                #pragma unroll
                for (int c2 = 0; c2 < 2; ++c2) {
                    f32x2 b01 = { bv0[c2 * 2], bv0[c2 * 2 + 1] };
                    f32x2 t01 = ar + b01;                      // v_pk_add_f32 (exact)
                    acc[r][c2 * 2]     = fmaf(fabsf(t01[0]), w, acc[r][c2 * 2]);
                    acc[r][c2 * 2 + 1] = fmaf(fabsf(t01[1]), w, acc[r][c2 * 2 + 1]);
                    f32x2 b23 = { bv1[c2 * 2], bv1[c2 * 2 + 1] };
                    f32x2 t23 = ar + b23;
                    acc[r][c2 * 2 + 4] = fmaf(fabsf(t23[0]), w, acc[r][c2 * 2 + 4]);
                    acc[r][c2 * 2 + 5] = fmaf(fabsf(t23[1]), w, acc[r][c2 * 2 + 5]);
                }
            }
        }
    }

    // logit = 0.5*(ri + rj + abssum) + b2; x = -log2(e)*logit; y = 1/(1+2^x)
    const float C = -0.72134752f;                 // -log2(e)/2
    const float base = -1.44269504f * b2[0];
    float riC[4], rjC[8];
    #pragma unroll
    for (int r = 0; r < 4; ++r) riC[r] = fmaf(ris[ty * 4 + r], C, base);
    #pragma unroll
    for (int c = 0; c < 4; ++c) {
        rjC[c]     = rjs[tx * 4 + c] * C;
        rjC[c + 4] = rjs[64 + tx * 4 + c] * C;
    }

    #pragma unroll
    for (int r = 0; r < 4; ++r) {
        f32x4 o0, o1;
        #pragma unroll
        for (int c = 0; c < 4; ++c) {
            float x0 = fmaf(acc[r][c],     C, riC[r] + rjC[c]);
            float x1 = fmaf(acc[r][c + 4], C, riC[r] + rjC[c + 4]);
            o0[c] = __builtin_amdgcn_rcpf(1.0f + __builtin_amdgcn_exp2f(x0));
            o1[c] = __builtin_amdgcn_rcpf(1.0f + __builtin_amdgcn_exp2f(x1));
        }
        float* orow = out + (i0 + ty * 4 + r) * N + j0 + tx * 4;
        __builtin_nontemporal_store(o0, (f32x4*)orow);         // write-once output,
        __builtin_nontemporal_store(o1, (f32x4*)(orow + 64));  // keep L2 for z/W1
    }
}

extern "C" void kernel_launch(void* const* d_in, const int* in_sizes, int n_in,
                              void* d_out, int out_size, void* d_ws, size_t ws_size,
                              hipStream_t stream) {
    const float* z  = (const float*)d_in[0];
    const float* W1 = (const float*)d_in[1];
    const float* b1 = (const float*)d_in[2];
    const float* W2 = (const float*)d_in[3];
    const float* b2 = (const float*)d_in[4];
    float* out = (float*)d_out;
    (void)d_ws; (void)ws_size;   // workspace no longer needed

    edge_fused<<<dim3(N / 128, N / 64), 256, 0, stream>>>(z, W1, b1, W2, b2, out);
}